// Round 5
// baseline (997.480 us; speedup 1.0000x reference)
//
#include <hip/hip_runtime.h>
#include <cstdint>

// SREChead: stem 1x1 (128->64) + 2x 3x3 (64->64), each BN+SiLU, then 1x1
// reg(4)/obj(1) heads + YOLOX decode. B=64, 80x80, stride 32.
// R11: fused single-launch kernel, LEAF version. R10 diagnostic showed
// kernel work is only ~141us of the 443us total -- ~300us is per-dispatch
// overhead (~80us per extra launch; R9 single-launch overhead was 59us).
// R9's fused attempt spilled (VGPR 84, +0.5GB scratch traffic) -- suspect
// cg::grid.sync()'s real function call made the kernel non-leaf and wrecked
// regalloc. This version uses a hand-rolled device-scope generation barrier
// (AGENT-scope __hip_atomic, self-resetting; counters memset per launch),
// keeping the kernel a leaf. Launched cooperatively for co-residency.
// Phase bodies identical to R8 (proven). Fallback: R8 4-kernel path.

typedef short short8 __attribute__((ext_vector_type(8)));
typedef float floatx4 __attribute__((ext_vector_type(4)));
typedef float fx4 __attribute__((ext_vector_type(4)));
typedef unsigned short us4 __attribute__((ext_vector_type(4)));
typedef unsigned uint4v __attribute__((ext_vector_type(4)));
typedef unsigned uint2v __attribute__((ext_vector_type(2)));

#define NPIX 6400
#define CGS  3952    // conv tile granule stride: 494 px * 8 us (6x82=492 used)
#define CGS2 2576    // h-tile granule stride: 322 px * 8 us (320 used)

static __device__ __forceinline__ unsigned short f2bf(float f) {
    unsigned u = __builtin_bit_cast(unsigned, f);
    u += 0x7fffu + ((u >> 16) & 1u);      // round-to-nearest-even
    return (unsigned short)(u >> 16);
}

// packed bf16 convert: lo16 = bf16(a), hi16 = bf16(b); RTNE
static __device__ __forceinline__ unsigned cvt_pk_bf16(float a, float b) {
    unsigned r;
    asm("v_cvt_pk_bf16_f32 %0, %1, %2" : "=v"(r) : "v"(a), "v"(b));
    return r;
}

static __device__ __forceinline__ float silu_(float v) {
    return v / (1.0f + __expf(-v));
}

// ---------------------------------------------------------------------------
// Leaf grid barrier: generation-based, self-resetting (cnt returns to 0 so
// only the first-ever use needs memset; we memset each launch anyway since
// the harness re-poisons the workspace). AGENT-scope acq/rel atomics give
// cross-XCD visibility of f1/f2 (same semantics cg::grid.sync used in R9,
// which passed verification).
static __device__ __forceinline__ void grid_bar(unsigned* cnt, unsigned* gen,
                                                unsigned nblk) {
    __syncthreads();
    if (threadIdx.x == 0) {
        unsigned g = __hip_atomic_load(gen, __ATOMIC_RELAXED,
                                       __HIP_MEMORY_SCOPE_AGENT);
        unsigned a = __hip_atomic_fetch_add(cnt, 1u, __ATOMIC_ACQ_REL,
                                            __HIP_MEMORY_SCOPE_AGENT);
        if (a == nblk - 1u) {
            __hip_atomic_store(cnt, 0u, __ATOMIC_RELAXED,
                               __HIP_MEMORY_SCOPE_AGENT);
            __hip_atomic_fetch_add(gen, 1u, __ATOMIC_RELEASE,
                                   __HIP_MEMORY_SCOPE_AGENT);
        } else {
            while (__hip_atomic_load(gen, __ATOMIC_ACQUIRE,
                                     __HIP_MEMORY_SCOPE_AGENT) == g)
                __builtin_amdgcn_s_sleep(1);
        }
    }
    __syncthreads();
}

// ---------------------------------------------------------------------------
// Phase bodies (shared by mega2 and the fallback path) -- R8-proven.
// ---------------------------------------------------------------------------
static __device__ __forceinline__ void rearr_elem(
    int idx, const float* __restrict__ ws_, const float* __restrict__ w1,
    const float* __restrict__ w2,
    unsigned short* __restrict__ wS, unsigned short* __restrict__ wB1,
    unsigned short* __restrict__ wB2) {
    if (idx < 8192) {
        int e = idx;
        int j = e & 7, lane = (e >> 3) & 63, ct = (e >> 9) & 3, kb = e >> 11;
        int co = ct * 16 + (lane & 15);
        int ci = kb * 32 + ((lane >> 4) * 8) + j;
        wS[e] = f2bf(ws_[co * 128 + ci]);
        return;
    }
    idx -= 8192;
    const float* src = (idx < 36864) ? w1 : w2;
    unsigned short* dst = (idx < 36864) ? wB1 : wB2;
    int e = (idx < 36864) ? idx : idx - 36864;
    int j = e & 7, lane = (e >> 3) & 63, ct = (e >> 9) & 3, kb = e >> 11;
    int co = ct * 16 + (lane & 15);
    int k = kb * 32 + ((lane >> 4) * 8) + j;
    int ci = k & 63, tap = k >> 6;
    dst[e] = f2bf(src[(co * 64 + ci) * 9 + tap]);
}

// Stem tile (128 px of image b): LDS-free, fragments direct from global.
static __device__ __forceinline__ void stem_tile(
    const float* __restrict__ x, const unsigned short* __restrict__ wS,
    const float* __restrict__ scale, const float* __restrict__ shift,
    unsigned short* __restrict__ f1, int b, int pbase,
    int lane, int wv, int l15, int q) {
    floatx4 acc[4][2];   // [ct][t]
    floatx4 zf = {0.0f, 0.0f, 0.0f, 0.0f};
    #pragma unroll
    for (int ct = 0; ct < 4; ++ct)
        #pragma unroll
        for (int t = 0; t < 2; ++t) acc[ct][t] = zf;

    const float* xb = x + (size_t)b * 128 * NPIX + pbase + wv * 32 + l15;

    #pragma unroll
    for (int kb = 0; kb < 4; ++kb) {
        short8 wf[4];
        #pragma unroll
        for (int ct = 0; ct < 4; ++ct)
            wf[ct] = *(const short8*)(wS + ((kb * 4 + ct) * 64 + lane) * 8);
        short8 xf[2];
        #pragma unroll
        for (int t = 0; t < 2; ++t) {
            const float* src = xb + (size_t)(kb * 32 + q * 8) * NPIX + t * 16;
            float v[8];
            #pragma unroll
            for (int j = 0; j < 8; ++j) v[j] = src[(size_t)j * NPIX];
            uint4v u;
            #pragma unroll
            for (int j = 0; j < 4; ++j) u[j] = cvt_pk_bf16(v[2 * j], v[2 * j + 1]);
            xf[t] = __builtin_bit_cast(short8, u);
        }
        #pragma unroll
        for (int ct = 0; ct < 4; ++ct)
            #pragma unroll
            for (int t = 0; t < 2; ++t)
                acc[ct][t] = __builtin_amdgcn_mfma_f32_16x16x32_bf16(
                    wf[ct], xf[t], acc[ct][t], 0, 0, 0);
    }

    float sc[4][4], sh[4][4];
    #pragma unroll
    for (int ct = 0; ct < 4; ++ct)
        #pragma unroll
        for (int r = 0; r < 4; ++r) {
            sc[ct][r] = scale[ct * 16 + q * 4 + r];
            sh[ct][r] = shift[ct * 16 + q * 4 + r];
        }

    #pragma unroll
    for (int t = 0; t < 2; ++t) {
        int pg = pbase + (wv * 2 + t) * 16 + l15;
        unsigned short* dst = f1 + ((size_t)b * NPIX + pg) * 64;
        #pragma unroll
        for (int ct = 0; ct < 4; ++ct) {
            float r0 = silu_(acc[ct][t][0] * sc[ct][0] + sh[ct][0]);
            float r1 = silu_(acc[ct][t][1] * sc[ct][1] + sh[ct][1]);
            float r2 = silu_(acc[ct][t][2] * sc[ct][2] + sh[ct][2]);
            float r3 = silu_(acc[ct][t][3] * sc[ct][3] + sh[ct][3]);
            uint2v p2 = {cvt_pk_bf16(r0, r1), cvt_pk_bf16(r2, r3)};
            *(us4*)(dst + ct * 16 + q * 4) = __builtin_bit_cast(us4, p2);
        }
    }
}

// Conv core, 4-ct N-blocking (R6 structure). Unconditional sync before each
// half's staging: protects WAR against the previous half AND the previous
// grid-stride iteration's tail reads of the same LDS tile.
static __device__ __forceinline__ void conv_core(
    const unsigned short* __restrict__ fin, const unsigned short* __restrict__ wB,
    unsigned short* tile, floatx4 (*acc)[5], int b, int y0,
    int tid, int lane, int wv, int l15, int q) {
    const unsigned short* fb = fin + (size_t)b * NPIX * 64;
    floatx4 zf = {0.0f, 0.0f, 0.0f, 0.0f};
    #pragma unroll
    for (int c4 = 0; c4 < 4; ++c4)
        #pragma unroll
        for (int pt = 0; pt < 5; ++pt) acc[c4][pt] = zf;

    #pragma unroll
    for (int half = 0; half < 2; ++half) {
        __syncthreads();               // WAR: previous reads of tile done
        #pragma unroll
        for (int i = 0; i < 8; ++i) {
            int cid = i * 256 + tid;   // 1968 = 492 pix * 4 granules
            if (cid < 1968) {
                int pixL = cid >> 2, g = cid & 3;
                int r = pixL / 82, c = pixL - r * 82;
                int gy = y0 - 1 + r, gx = c - 1;
                short8 v = {};
                if ((unsigned)gy < 80u && (unsigned)gx < 80u)
                    v = *(const short8*)(
                        fb + (size_t)(gy * 80 + gx) * 64 + half * 32 + g * 8);
                *(short8*)(tile + g * CGS + pixL * 8) = v;
            }
        }
        __syncthreads();

        #pragma unroll
        for (int trow = 0; trow < 3; ++trow) {
            const int dy = trow - 1;
            #pragma unroll
            for (int tc = 0; tc < 3; ++tc) {
                const int dx = tc - 1;
                const int kb = (trow * 3 + tc) * 2 + half;
                short8 w4[4];
                #pragma unroll
                for (int c4 = 0; c4 < 4; ++c4)
                    w4[c4] = *(const short8*)(wB + ((kb * 4 + c4) * 64 + lane) * 8);
                #pragma unroll
                for (int pt = 0; pt < 5; ++pt) {
                    int pix = (wv + 1 + dy) * 82 + pt * 16 + l15 + 1 + dx;
                    short8 b8 = *(const short8*)(tile + q * CGS + pix * 8);
                    #pragma unroll
                    for (int c4 = 0; c4 < 4; ++c4)
                        acc[c4][pt] = __builtin_amdgcn_mfma_f32_16x16x32_bf16(
                            w4[c4], b8, acc[c4][pt], 0, 0, 0);
                }
            }
        }
    }
}

// conv3 tile: conv + BN/SiLU epilogue to fout (NHWC bf16).
static __device__ __forceinline__ void conv3_tile(
    const unsigned short* __restrict__ fin, const unsigned short* __restrict__ wB,
    const float* __restrict__ scale, const float* __restrict__ shift,
    unsigned short* __restrict__ fout, unsigned short* tile, int b, int y0,
    int tid, int lane, int wv, int l15, int q) {
    floatx4 acc[4][5];
    conv_core(fin, wB, tile, acc, b, y0, tid, lane, wv, l15, q);

    float sc4[4][4], sh4[4][4];
    #pragma unroll
    for (int c4 = 0; c4 < 4; ++c4)
        #pragma unroll
        for (int r = 0; r < 4; ++r) {
            sc4[c4][r] = scale[c4 * 16 + q * 4 + r];
            sh4[c4][r] = shift[c4 * 16 + q * 4 + r];
        }
    #pragma unroll
    for (int pt = 0; pt < 5; ++pt) {
        int pg = (y0 + wv) * 80 + pt * 16 + l15;
        unsigned short* dst = fout + ((size_t)b * NPIX + pg) * 64;
        #pragma unroll
        for (int c4 = 0; c4 < 4; ++c4) {
            float r0 = silu_(acc[c4][pt][0] * sc4[c4][0] + sh4[c4][0]);
            float r1 = silu_(acc[c4][pt][1] * sc4[c4][1] + sh4[c4][1]);
            float r2 = silu_(acc[c4][pt][2] * sc4[c4][2] + sh4[c4][2]);
            float r3 = silu_(acc[c4][pt][3] * sc4[c4][3] + sh4[c4][3]);
            uint2v p2 = {cvt_pk_bf16(r0, r1), cvt_pk_bf16(r2, r3)};
            *(us4*)(dst + c4 * 16 + q * 4) = __builtin_bit_cast(us4, p2);
        }
    }
}

// conv2 + heads + YOLOX decode tile.
static __device__ __forceinline__ void head_tile(
    const unsigned short* __restrict__ fin, const unsigned short* __restrict__ wB,
    const float* __restrict__ scale, const float* __restrict__ shift,
    const float* __restrict__ reg_w, const float* __restrict__ reg_b,
    const float* __restrict__ obj_w, const float* __restrict__ obj_b,
    float* __restrict__ out, unsigned short* tile, int b, int y0,
    int tid, int lane, int wv, int l15, int q) {
    floatx4 acc[4][5];
    conv_core(fin, wB, tile, acc, b, y0, tid, lane, wv, l15, q);

    __syncthreads();   // conv reads done -> reuse LDS for h (stride CGS2)

    float sc4[4][4], sh4[4][4];
    #pragma unroll
    for (int c4 = 0; c4 < 4; ++c4)
        #pragma unroll
        for (int r = 0; r < 4; ++r) {
            sc4[c4][r] = scale[c4 * 16 + q * 4 + r];
            sh4[c4][r] = shift[c4 * 16 + q * 4 + r];
        }
    #pragma unroll
    for (int pt = 0; pt < 5; ++pt) {
        int pix = wv * 80 + pt * 16 + l15;   // block-local pixel 0..319
        #pragma unroll
        for (int c4 = 0; c4 < 4; ++c4) {
            int gco = c4 * 2 + (q >> 1);     // co>>3
            float r0 = silu_(acc[c4][pt][0] * sc4[c4][0] + sh4[c4][0]);
            float r1 = silu_(acc[c4][pt][1] * sc4[c4][1] + sh4[c4][1]);
            float r2 = silu_(acc[c4][pt][2] * sc4[c4][2] + sh4[c4][2]);
            float r3 = silu_(acc[c4][pt][3] * sc4[c4][3] + sh4[c4][3]);
            uint2v p2 = {cvt_pk_bf16(r0, r1), cvt_pk_bf16(r2, r3)};
            *(us4*)(tile + gco * CGS2 + pix * 8 + (q & 1) * 4) =
                __builtin_bit_cast(us4, p2);
        }
    }

    // head B-frags: B[k=co][n] = reg_w[n][co] (n<4), obj_w[co] (n==4), else 0
    short8 hbf[2];
    #pragma unroll
    for (int kb2 = 0; kb2 < 2; ++kb2) {
        int k0 = kb2 * 32 + q * 8;
        short8 f = {};
        if (l15 < 4) {
            #pragma unroll
            for (int j = 0; j < 8; ++j) f[j] = (short)f2bf(reg_w[l15 * 64 + k0 + j]);
        } else if (l15 == 4) {
            #pragma unroll
            for (int j = 0; j < 8; ++j) f[j] = (short)f2bf(obj_w[k0 + j]);
        }
        hbf[kb2] = f;
    }

    __syncthreads();

    floatx4 zf = {0.0f, 0.0f, 0.0f, 0.0f};
    floatx4 acc5[5];
    #pragma unroll
    for (int t = 0; t < 5; ++t) acc5[t] = zf;
    #pragma unroll
    for (int t = 0; t < 5; ++t) {
        int mt = wv * 5 + t;
        int pix = mt * 16 + l15;
        #pragma unroll
        for (int kb2 = 0; kb2 < 2; ++kb2) {
            short8 a = *(const short8*)(tile + (kb2 * 4 + q) * CGS2 + pix * 8);
            acc5[t] = __builtin_amdgcn_mfma_f32_16x16x32_bf16(
                a, hbf[kb2], acc5[t], 0, 0, 0);
        }
    }

    float bias = 0.0f;
    if (l15 < 4) bias = reg_b[l15];
    else if (l15 == 4) bias = obj_b[0];

    #pragma unroll
    for (int t = 0; t < 5; ++t) {
        int mt = wv * 5 + t;
        #pragma unroll
        for (int r = 0; r < 4; ++r) {
            int pixL = mt * 16 + q * 4 + r;
            if (l15 < 5) {
                float v = acc5[t][r] + bias;
                float gx = (float)(pixL % 80);
                float gy = (float)(y0 + pixL / 80);
                float o;
                if (l15 == 0)      o = (v + gx) * 32.0f;
                else if (l15 == 1) o = (v + gy) * 32.0f;
                else if (l15 < 4)  o = __expf(v) * 32.0f;
                else               o = 1.0f / (1.0f + __expf(-v));
                out[((size_t)b * NPIX + y0 * 80 + pixL) * 5 + l15] = o;
            }
        }
    }
}

// ---------------------------------------------------------------------------
// Fused leaf kernel: 4 phases, grid-stride, hand-rolled grid barrier.
// ---------------------------------------------------------------------------
__global__ __launch_bounds__(256, 3) void mega2_kernel(
    const float* __restrict__ x,
    const float* __restrict__ stem_w, const float* __restrict__ stem_scale,
    const float* __restrict__ stem_shift,
    const float* __restrict__ c1_w, const float* __restrict__ c1_scale,
    const float* __restrict__ c1_shift,
    const float* __restrict__ c2_w, const float* __restrict__ c2_scale,
    const float* __restrict__ c2_shift,
    const float* __restrict__ reg_w, const float* __restrict__ reg_b,
    const float* __restrict__ obj_w, const float* __restrict__ obj_b,
    float* __restrict__ out,
    unsigned short* __restrict__ wS, unsigned short* __restrict__ wB1,
    unsigned short* __restrict__ wB2, unsigned short* __restrict__ f1,
    unsigned short* __restrict__ f2, unsigned* __restrict__ bar) {
    __shared__ __align__(16) unsigned short tile[8 * CGS2];  // 41216 B
    int tid = threadIdx.x;
    int lane = tid & 63, wv = tid >> 6;
    int l15 = lane & 15, q = lane >> 4;
    unsigned gsz = gridDim.x;

    // phase 0: weight rearrange
    for (int idx = blockIdx.x * 256 + tid; idx < 81920; idx += gsz * 256)
        rearr_elem(idx, stem_w, c1_w, c2_w, wS, wB1, wB2);
    grid_bar(bar + 0, bar + 1, gsz);

    // phase 1: stem (3200 tiles of 128 px; 640 blocks -> 5 each)
    for (unsigned t = blockIdx.x; t < 3200; t += gsz) {
        int b = t / 50, pbase = (t - b * 50) * 128;
        stem_tile(x, wS, stem_scale, stem_shift, f1, b, pbase, lane, wv, l15, q);
    }
    grid_bar(bar + 2, bar + 3, gsz);

    // phase 2: conv1 (1280 tiles of 4 rows; 640 blocks -> 2 each)
    for (unsigned t = blockIdx.x; t < 1280; t += gsz) {
        int b = t / 20, y0 = (t - b * 20) * 4;
        conv3_tile(f1, wB1, c1_scale, c1_shift, f2, tile, b, y0,
                   tid, lane, wv, l15, q);
    }
    grid_bar(bar + 4, bar + 5, gsz);

    // phase 3: conv2 + heads + decode
    for (unsigned t = blockIdx.x; t < 1280; t += gsz) {
        int b = t / 20, y0 = (t - b * 20) * 4;
        head_tile(f2, wB2, c2_scale, c2_shift, reg_w, reg_b, obj_w, obj_b,
                  out, tile, b, y0, tid, lane, wv, l15, q);
    }
}

// ---------------------------------------------------------------------------
// Fallback standalone kernels (identical phase bodies).
// ---------------------------------------------------------------------------
__global__ __launch_bounds__(256) void rearr_w_kernel(
    const float* __restrict__ ws_, const float* __restrict__ w1,
    const float* __restrict__ w2,
    unsigned short* __restrict__ wS, unsigned short* __restrict__ wB1,
    unsigned short* __restrict__ wB2) {
    int idx = blockIdx.x * 256 + threadIdx.x;
    if (idx < 81920) rearr_elem(idx, ws_, w1, w2, wS, wB1, wB2);
}

__global__ __launch_bounds__(256) void stem_kernel(
    const float* __restrict__ x, const unsigned short* __restrict__ wS,
    const float* __restrict__ scale, const float* __restrict__ shift,
    unsigned short* __restrict__ f1) {
    int tid = threadIdx.x;
    int lane = tid & 63, wv = tid >> 6;
    stem_tile(x, wS, scale, shift, f1, blockIdx.y, blockIdx.x * 128,
              lane, wv, lane & 15, lane >> 4);
}

__global__ __launch_bounds__(256, 3) void conv3_kernel(
    const unsigned short* __restrict__ fin, const unsigned short* __restrict__ wB,
    const float* __restrict__ scale, const float* __restrict__ shift,
    unsigned short* __restrict__ fout) {
    __shared__ __align__(16) unsigned short tile[8 * CGS2];
    int tid = threadIdx.x;
    int lane = tid & 63, wv = tid >> 6;
    conv3_tile(fin, wB, scale, shift, fout, tile, blockIdx.y, blockIdx.x * 4,
               tid, lane, wv, lane & 15, lane >> 4);
}

__global__ __launch_bounds__(256, 3) void conv_head_kernel(
    const unsigned short* __restrict__ fin, const unsigned short* __restrict__ wB,
    const float* __restrict__ scale, const float* __restrict__ shift,
    const float* __restrict__ reg_w, const float* __restrict__ reg_b,
    const float* __restrict__ obj_w, const float* __restrict__ obj_b,
    float* __restrict__ out) {
    __shared__ __align__(16) unsigned short tile[8 * CGS2];
    int tid = threadIdx.x;
    int lane = tid & 63, wv = tid >> 6;
    head_tile(fin, wB, scale, shift, reg_w, reg_b, obj_w, obj_b, out, tile,
              blockIdx.y, blockIdx.x * 4, tid, lane, wv, lane & 15, lane >> 4);
}

// ---------------------------------------------------------------------------
extern "C" void kernel_launch(void* const* d_in, const int* in_sizes, int n_in,
                              void* d_out, int out_size, void* d_ws, size_t ws_size,
                              hipStream_t stream) {
    const float* x          = (const float*)d_in[0];
    const float* stem_w     = (const float*)d_in[1];
    const float* stem_scale = (const float*)d_in[2];
    const float* stem_shift = (const float*)d_in[3];
    const float* c1_w       = (const float*)d_in[4];
    const float* c1_scale   = (const float*)d_in[5];
    const float* c1_shift   = (const float*)d_in[6];
    const float* c2_w       = (const float*)d_in[7];
    const float* c2_scale   = (const float*)d_in[8];
    const float* c2_shift   = (const float*)d_in[9];
    const float* reg_w      = (const float*)d_in[10];
    const float* reg_b      = (const float*)d_in[11];
    const float* obj_w      = (const float*)d_in[12];
    const float* obj_b      = (const float*)d_in[13];
    float* out = (float*)d_out;

    // ws (ushort units): wS[8192] | wB1[36864] | wB2[36864] | f1 | f2 | bar
    const size_t needed =
        ((size_t)8192 + 73728 + 2 * (size_t)64 * NPIX * 64 + 32) * 2;
    if (ws_size < needed) return;

    unsigned short* ws  = (unsigned short*)d_ws;
    unsigned short* wS  = ws;
    unsigned short* wB1 = ws + 8192;
    unsigned short* wB2 = wB1 + 36864;
    unsigned short* f1  = wB2 + 36864;
    unsigned short* f2  = f1 + (size_t)64 * NPIX * 64;
    unsigned*       bar = (unsigned*)(f2 + (size_t)64 * NPIX * 64);

    // grid: 640 blocks (2.5/CU) divides conv 1280 and stem 3200 exactly.
    static int nblk = -1;
    if (nblk < 0) {
        int perCU = 0;
        if (hipOccupancyMaxActiveBlocksPerMultiprocessor(
                &perCU, (const void*)mega2_kernel, 256, 0) != hipSuccess)
            perCU = 0;
        int cap = perCU * 256;
        nblk = (cap >= 640) ? 640 : (cap >= 512 ? 512 : (cap >= 256 ? 256 : 0));
    }

    hipError_t e = hipErrorUnknown;
    if (nblk > 0) {
        hipMemsetAsync(bar, 0, 8 * sizeof(unsigned), stream);
        void* args[] = {
            (void*)&x,
            (void*)&stem_w, (void*)&stem_scale, (void*)&stem_shift,
            (void*)&c1_w, (void*)&c1_scale, (void*)&c1_shift,
            (void*)&c2_w, (void*)&c2_scale, (void*)&c2_shift,
            (void*)&reg_w, (void*)&reg_b, (void*)&obj_w, (void*)&obj_b,
            (void*)&out,
            (void*)&wS, (void*)&wB1, (void*)&wB2, (void*)&f1, (void*)&f2,
            (void*)&bar};
        e = hipLaunchCooperativeKernel(
            (const void*)mega2_kernel, dim3(nblk), dim3(256), args, 0, stream);
    }

    if (e != hipSuccess) {
        // fallback: proven 4-kernel path (R8)
        rearr_w_kernel<<<320, 256, 0, stream>>>(stem_w, c1_w, c2_w, wS, wB1, wB2);
        stem_kernel<<<dim3(50, 64), 256, 0, stream>>>(x, wS, stem_scale,
                                                      stem_shift, f1);
        conv3_kernel<<<dim3(20, 64), 256, 0, stream>>>(f1, wB1, c1_scale,
                                                       c1_shift, f2);
        conv_head_kernel<<<dim3(20, 64), 256, 0, stream>>>(
            f2, wB2, c2_scale, c2_shift, reg_w, reg_b, obj_w, obj_b, out);
    }
}

// Round 6
// 834.730 us; speedup vs baseline: 1.1950x; 1.1950x over previous
//
#include <hip/hip_runtime.h>
#include <cstdint>

// SREChead: stem 1x1 (128->64) + 2x 3x3 (64->64), each BN+SiLU, then 1x1
// reg(4)/obj(1) heads + YOLOX decode. B=64, 80x80, stride 32.
// R12: fused kernel, third attempt. R11 falsified the "non-leaf barrier"
// theory (identical VGPR 84 / 4.3M conflicts / +450MB traffic with a leaf
// barrier). Two fixes this round:
//  (1) __launch_bounds__(256,2) on the fused kernel (was (256,3)): the
//      phase-union's peak pressure (conv acc[4][5]=80 regs + operands)
//      cannot fit the 3-waves/EU VGPR cap -> scratch spill (+320MB writes).
//      (256,2) raises the cap to 256 VGPRs.
//  (2) quiet barrier spin: RELAXED polling + s_sleep(8), single ACQUIRE
//      load on exit (R11 spun on ACQUIRE -> per-poll cache invalidates
//      grid-wide -> FETCH 580MB vs ~370 logical).
// Phase bodies identical to R8 (proven). Fallback: R8 4-kernel path.

typedef short short8 __attribute__((ext_vector_type(8)));
typedef float floatx4 __attribute__((ext_vector_type(4)));
typedef float fx4 __attribute__((ext_vector_type(4)));
typedef unsigned short us4 __attribute__((ext_vector_type(4)));
typedef unsigned uint4v __attribute__((ext_vector_type(4)));
typedef unsigned uint2v __attribute__((ext_vector_type(2)));

#define NPIX 6400
#define CGS  3952    // conv tile granule stride: 494 px * 8 us (6x82=492 used)
#define CGS2 2576    // h-tile granule stride: 322 px * 8 us (320 used)

static __device__ __forceinline__ unsigned short f2bf(float f) {
    unsigned u = __builtin_bit_cast(unsigned, f);
    u += 0x7fffu + ((u >> 16) & 1u);      // round-to-nearest-even
    return (unsigned short)(u >> 16);
}

// packed bf16 convert: lo16 = bf16(a), hi16 = bf16(b); RTNE
static __device__ __forceinline__ unsigned cvt_pk_bf16(float a, float b) {
    unsigned r;
    asm("v_cvt_pk_bf16_f32 %0, %1, %2" : "=v"(r) : "v"(a), "v"(b));
    return r;
}

static __device__ __forceinline__ float silu_(float v) {
    return v / (1.0f + __expf(-v));
}

// ---------------------------------------------------------------------------
// Leaf grid barrier, quiet spin: RELAXED poll + s_sleep; one ACQUIRE on exit.
// Generation-based, self-resetting; counters memset per launch.
static __device__ __forceinline__ void grid_bar(unsigned* cnt, unsigned* gen,
                                                unsigned nblk) {
    __syncthreads();
    if (threadIdx.x == 0) {
        unsigned g = __hip_atomic_load(gen, __ATOMIC_RELAXED,
                                       __HIP_MEMORY_SCOPE_AGENT);
        unsigned a = __hip_atomic_fetch_add(cnt, 1u, __ATOMIC_ACQ_REL,
                                            __HIP_MEMORY_SCOPE_AGENT);
        if (a == nblk - 1u) {
            __hip_atomic_store(cnt, 0u, __ATOMIC_RELAXED,
                               __HIP_MEMORY_SCOPE_AGENT);
            __hip_atomic_fetch_add(gen, 1u, __ATOMIC_RELEASE,
                                   __HIP_MEMORY_SCOPE_AGENT);
        } else {
            while (__hip_atomic_load(gen, __ATOMIC_RELAXED,
                                     __HIP_MEMORY_SCOPE_AGENT) == g)
                __builtin_amdgcn_s_sleep(8);
            (void)__hip_atomic_load(gen, __ATOMIC_ACQUIRE,
                                    __HIP_MEMORY_SCOPE_AGENT);  // acq fence
        }
    }
    __syncthreads();
}

// ---------------------------------------------------------------------------
// Phase bodies (shared by mega3 and the fallback path) -- R8-proven.
// ---------------------------------------------------------------------------
static __device__ __forceinline__ void rearr_elem(
    int idx, const float* __restrict__ ws_, const float* __restrict__ w1,
    const float* __restrict__ w2,
    unsigned short* __restrict__ wS, unsigned short* __restrict__ wB1,
    unsigned short* __restrict__ wB2) {
    if (idx < 8192) {
        int e = idx;
        int j = e & 7, lane = (e >> 3) & 63, ct = (e >> 9) & 3, kb = e >> 11;
        int co = ct * 16 + (lane & 15);
        int ci = kb * 32 + ((lane >> 4) * 8) + j;
        wS[e] = f2bf(ws_[co * 128 + ci]);
        return;
    }
    idx -= 8192;
    const float* src = (idx < 36864) ? w1 : w2;
    unsigned short* dst = (idx < 36864) ? wB1 : wB2;
    int e = (idx < 36864) ? idx : idx - 36864;
    int j = e & 7, lane = (e >> 3) & 63, ct = (e >> 9) & 3, kb = e >> 11;
    int co = ct * 16 + (lane & 15);
    int k = kb * 32 + ((lane >> 4) * 8) + j;
    int ci = k & 63, tap = k >> 6;
    dst[e] = f2bf(src[(co * 64 + ci) * 9 + tap]);
}

// Stem tile (128 px of image b): LDS-free, fragments direct from global.
static __device__ __forceinline__ void stem_tile(
    const float* __restrict__ x, const unsigned short* __restrict__ wS,
    const float* __restrict__ scale, const float* __restrict__ shift,
    unsigned short* __restrict__ f1, int b, int pbase,
    int lane, int wv, int l15, int q) {
    floatx4 acc[4][2];   // [ct][t]
    floatx4 zf = {0.0f, 0.0f, 0.0f, 0.0f};
    #pragma unroll
    for (int ct = 0; ct < 4; ++ct)
        #pragma unroll
        for (int t = 0; t < 2; ++t) acc[ct][t] = zf;

    const float* xb = x + (size_t)b * 128 * NPIX + pbase + wv * 32 + l15;

    #pragma unroll
    for (int kb = 0; kb < 4; ++kb) {
        short8 wf[4];
        #pragma unroll
        for (int ct = 0; ct < 4; ++ct)
            wf[ct] = *(const short8*)(wS + ((kb * 4 + ct) * 64 + lane) * 8);
        short8 xf[2];
        #pragma unroll
        for (int t = 0; t < 2; ++t) {
            const float* src = xb + (size_t)(kb * 32 + q * 8) * NPIX + t * 16;
            float v[8];
            #pragma unroll
            for (int j = 0; j < 8; ++j) v[j] = src[(size_t)j * NPIX];
            uint4v u;
            #pragma unroll
            for (int j = 0; j < 4; ++j) u[j] = cvt_pk_bf16(v[2 * j], v[2 * j + 1]);
            xf[t] = __builtin_bit_cast(short8, u);
        }
        #pragma unroll
        for (int ct = 0; ct < 4; ++ct)
            #pragma unroll
            for (int t = 0; t < 2; ++t)
                acc[ct][t] = __builtin_amdgcn_mfma_f32_16x16x32_bf16(
                    wf[ct], xf[t], acc[ct][t], 0, 0, 0);
    }

    float sc[4][4], sh[4][4];
    #pragma unroll
    for (int ct = 0; ct < 4; ++ct)
        #pragma unroll
        for (int r = 0; r < 4; ++r) {
            sc[ct][r] = scale[ct * 16 + q * 4 + r];
            sh[ct][r] = shift[ct * 16 + q * 4 + r];
        }

    #pragma unroll
    for (int t = 0; t < 2; ++t) {
        int pg = pbase + (wv * 2 + t) * 16 + l15;
        unsigned short* dst = f1 + ((size_t)b * NPIX + pg) * 64;
        #pragma unroll
        for (int ct = 0; ct < 4; ++ct) {
            float r0 = silu_(acc[ct][t][0] * sc[ct][0] + sh[ct][0]);
            float r1 = silu_(acc[ct][t][1] * sc[ct][1] + sh[ct][1]);
            float r2 = silu_(acc[ct][t][2] * sc[ct][2] + sh[ct][2]);
            float r3 = silu_(acc[ct][t][3] * sc[ct][3] + sh[ct][3]);
            uint2v p2 = {cvt_pk_bf16(r0, r1), cvt_pk_bf16(r2, r3)};
            *(us4*)(dst + ct * 16 + q * 4) = __builtin_bit_cast(us4, p2);
        }
    }
}

// Conv core, 4-ct N-blocking (R6 structure). Unconditional sync before each
// half's staging: protects WAR against the previous half AND the previous
// grid-stride iteration's tail reads of the same LDS tile.
static __device__ __forceinline__ void conv_core(
    const unsigned short* __restrict__ fin, const unsigned short* __restrict__ wB,
    unsigned short* tile, floatx4 (*acc)[5], int b, int y0,
    int tid, int lane, int wv, int l15, int q) {
    const unsigned short* fb = fin + (size_t)b * NPIX * 64;
    floatx4 zf = {0.0f, 0.0f, 0.0f, 0.0f};
    #pragma unroll
    for (int c4 = 0; c4 < 4; ++c4)
        #pragma unroll
        for (int pt = 0; pt < 5; ++pt) acc[c4][pt] = zf;

    #pragma unroll
    for (int half = 0; half < 2; ++half) {
        __syncthreads();               // WAR: previous reads of tile done
        #pragma unroll
        for (int i = 0; i < 8; ++i) {
            int cid = i * 256 + tid;   // 1968 = 492 pix * 4 granules
            if (cid < 1968) {
                int pixL = cid >> 2, g = cid & 3;
                int r = pixL / 82, c = pixL - r * 82;
                int gy = y0 - 1 + r, gx = c - 1;
                short8 v = {};
                if ((unsigned)gy < 80u && (unsigned)gx < 80u)
                    v = *(const short8*)(
                        fb + (size_t)(gy * 80 + gx) * 64 + half * 32 + g * 8);
                *(short8*)(tile + g * CGS + pixL * 8) = v;
            }
        }
        __syncthreads();

        #pragma unroll
        for (int trow = 0; trow < 3; ++trow) {
            const int dy = trow - 1;
            #pragma unroll
            for (int tc = 0; tc < 3; ++tc) {
                const int dx = tc - 1;
                const int kb = (trow * 3 + tc) * 2 + half;
                short8 w4[4];
                #pragma unroll
                for (int c4 = 0; c4 < 4; ++c4)
                    w4[c4] = *(const short8*)(wB + ((kb * 4 + c4) * 64 + lane) * 8);
                #pragma unroll
                for (int pt = 0; pt < 5; ++pt) {
                    int pix = (wv + 1 + dy) * 82 + pt * 16 + l15 + 1 + dx;
                    short8 b8 = *(const short8*)(tile + q * CGS + pix * 8);
                    #pragma unroll
                    for (int c4 = 0; c4 < 4; ++c4)
                        acc[c4][pt] = __builtin_amdgcn_mfma_f32_16x16x32_bf16(
                            w4[c4], b8, acc[c4][pt], 0, 0, 0);
                }
            }
        }
    }
}

// conv3 tile: conv + BN/SiLU epilogue to fout (NHWC bf16).
static __device__ __forceinline__ void conv3_tile(
    const unsigned short* __restrict__ fin, const unsigned short* __restrict__ wB,
    const float* __restrict__ scale, const float* __restrict__ shift,
    unsigned short* __restrict__ fout, unsigned short* tile, int b, int y0,
    int tid, int lane, int wv, int l15, int q) {
    floatx4 acc[4][5];
    conv_core(fin, wB, tile, acc, b, y0, tid, lane, wv, l15, q);

    float sc4[4][4], sh4[4][4];
    #pragma unroll
    for (int c4 = 0; c4 < 4; ++c4)
        #pragma unroll
        for (int r = 0; r < 4; ++r) {
            sc4[c4][r] = scale[c4 * 16 + q * 4 + r];
            sh4[c4][r] = shift[c4 * 16 + q * 4 + r];
        }
    #pragma unroll
    for (int pt = 0; pt < 5; ++pt) {
        int pg = (y0 + wv) * 80 + pt * 16 + l15;
        unsigned short* dst = fout + ((size_t)b * NPIX + pg) * 64;
        #pragma unroll
        for (int c4 = 0; c4 < 4; ++c4) {
            float r0 = silu_(acc[c4][pt][0] * sc4[c4][0] + sh4[c4][0]);
            float r1 = silu_(acc[c4][pt][1] * sc4[c4][1] + sh4[c4][1]);
            float r2 = silu_(acc[c4][pt][2] * sc4[c4][2] + sh4[c4][2]);
            float r3 = silu_(acc[c4][pt][3] * sc4[c4][3] + sh4[c4][3]);
            uint2v p2 = {cvt_pk_bf16(r0, r1), cvt_pk_bf16(r2, r3)};
            *(us4*)(dst + c4 * 16 + q * 4) = __builtin_bit_cast(us4, p2);
        }
    }
}

// conv2 + heads + YOLOX decode tile.
static __device__ __forceinline__ void head_tile(
    const unsigned short* __restrict__ fin, const unsigned short* __restrict__ wB,
    const float* __restrict__ scale, const float* __restrict__ shift,
    const float* __restrict__ reg_w, const float* __restrict__ reg_b,
    const float* __restrict__ obj_w, const float* __restrict__ obj_b,
    float* __restrict__ out, unsigned short* tile, int b, int y0,
    int tid, int lane, int wv, int l15, int q) {
    floatx4 acc[4][5];
    conv_core(fin, wB, tile, acc, b, y0, tid, lane, wv, l15, q);

    __syncthreads();   // conv reads done -> reuse LDS for h (stride CGS2)

    float sc4[4][4], sh4[4][4];
    #pragma unroll
    for (int c4 = 0; c4 < 4; ++c4)
        #pragma unroll
        for (int r = 0; r < 4; ++r) {
            sc4[c4][r] = scale[c4 * 16 + q * 4 + r];
            sh4[c4][r] = shift[c4 * 16 + q * 4 + r];
        }
    #pragma unroll
    for (int pt = 0; pt < 5; ++pt) {
        int pix = wv * 80 + pt * 16 + l15;   // block-local pixel 0..319
        #pragma unroll
        for (int c4 = 0; c4 < 4; ++c4) {
            int gco = c4 * 2 + (q >> 1);     // co>>3
            float r0 = silu_(acc[c4][pt][0] * sc4[c4][0] + sh4[c4][0]);
            float r1 = silu_(acc[c4][pt][1] * sc4[c4][1] + sh4[c4][1]);
            float r2 = silu_(acc[c4][pt][2] * sc4[c4][2] + sh4[c4][2]);
            float r3 = silu_(acc[c4][pt][3] * sc4[c4][3] + sh4[c4][3]);
            uint2v p2 = {cvt_pk_bf16(r0, r1), cvt_pk_bf16(r2, r3)};
            *(us4*)(tile + gco * CGS2 + pix * 8 + (q & 1) * 4) =
                __builtin_bit_cast(us4, p2);
        }
    }

    // head B-frags: B[k=co][n] = reg_w[n][co] (n<4), obj_w[co] (n==4), else 0
    short8 hbf[2];
    #pragma unroll
    for (int kb2 = 0; kb2 < 2; ++kb2) {
        int k0 = kb2 * 32 + q * 8;
        short8 f = {};
        if (l15 < 4) {
            #pragma unroll
            for (int j = 0; j < 8; ++j) f[j] = (short)f2bf(reg_w[l15 * 64 + k0 + j]);
        } else if (l15 == 4) {
            #pragma unroll
            for (int j = 0; j < 8; ++j) f[j] = (short)f2bf(obj_w[k0 + j]);
        }
        hbf[kb2] = f;
    }

    __syncthreads();

    floatx4 zf = {0.0f, 0.0f, 0.0f, 0.0f};
    floatx4 acc5[5];
    #pragma unroll
    for (int t = 0; t < 5; ++t) acc5[t] = zf;
    #pragma unroll
    for (int t = 0; t < 5; ++t) {
        int mt = wv * 5 + t;
        int pix = mt * 16 + l15;
        #pragma unroll
        for (int kb2 = 0; kb2 < 2; ++kb2) {
            short8 a = *(const short8*)(tile + (kb2 * 4 + q) * CGS2 + pix * 8);
            acc5[t] = __builtin_amdgcn_mfma_f32_16x16x32_bf16(
                a, hbf[kb2], acc5[t], 0, 0, 0);
        }
    }

    float bias = 0.0f;
    if (l15 < 4) bias = reg_b[l15];
    else if (l15 == 4) bias = obj_b[0];

    #pragma unroll
    for (int t = 0; t < 5; ++t) {
        int mt = wv * 5 + t;
        #pragma unroll
        for (int r = 0; r < 4; ++r) {
            int pixL = mt * 16 + q * 4 + r;
            if (l15 < 5) {
                float v = acc5[t][r] + bias;
                float gx = (float)(pixL % 80);
                float gy = (float)(y0 + pixL / 80);
                float o;
                if (l15 == 0)      o = (v + gx) * 32.0f;
                else if (l15 == 1) o = (v + gy) * 32.0f;
                else if (l15 < 4)  o = __expf(v) * 32.0f;
                else               o = 1.0f / (1.0f + __expf(-v));
                out[((size_t)b * NPIX + y0 * 80 + pixL) * 5 + l15] = o;
            }
        }
    }
}

// ---------------------------------------------------------------------------
// Fused leaf kernel: 4 phases, grid-stride, quiet grid barrier.
// __launch_bounds__(256,2): VGPR cap 256 -- phase-union pressure (conv
// acc[4][5] + operands) must NOT spill (R9/R11 at (256,3) spilled: VGPR 84,
// +320MB scratch writes).
// ---------------------------------------------------------------------------
__global__ __launch_bounds__(256, 2) void mega3_kernel(
    const float* __restrict__ x,
    const float* __restrict__ stem_w, const float* __restrict__ stem_scale,
    const float* __restrict__ stem_shift,
    const float* __restrict__ c1_w, const float* __restrict__ c1_scale,
    const float* __restrict__ c1_shift,
    const float* __restrict__ c2_w, const float* __restrict__ c2_scale,
    const float* __restrict__ c2_shift,
    const float* __restrict__ reg_w, const float* __restrict__ reg_b,
    const float* __restrict__ obj_w, const float* __restrict__ obj_b,
    float* __restrict__ out,
    unsigned short* __restrict__ wS, unsigned short* __restrict__ wB1,
    unsigned short* __restrict__ wB2, unsigned short* __restrict__ f1,
    unsigned short* __restrict__ f2, unsigned* __restrict__ bar) {
    __shared__ __align__(16) unsigned short tile[8 * CGS2];  // 41216 B
    int tid = threadIdx.x;
    int lane = tid & 63, wv = tid >> 6;
    int l15 = lane & 15, q = lane >> 4;
    unsigned gsz = gridDim.x;

    // phase 0: weight rearrange
    for (int idx = blockIdx.x * 256 + tid; idx < 81920; idx += gsz * 256)
        rearr_elem(idx, stem_w, c1_w, c2_w, wS, wB1, wB2);
    grid_bar(bar + 0, bar + 1, gsz);

    // phase 1: stem (3200 tiles of 128 px)
    for (unsigned t = blockIdx.x; t < 3200; t += gsz) {
        int b = t / 50, pbase = (t - b * 50) * 128;
        stem_tile(x, wS, stem_scale, stem_shift, f1, b, pbase, lane, wv, l15, q);
    }
    grid_bar(bar + 2, bar + 3, gsz);

    // phase 2: conv1 (1280 tiles of 4 rows)
    for (unsigned t = blockIdx.x; t < 1280; t += gsz) {
        int b = t / 20, y0 = (t - b * 20) * 4;
        conv3_tile(f1, wB1, c1_scale, c1_shift, f2, tile, b, y0,
                   tid, lane, wv, l15, q);
    }
    grid_bar(bar + 4, bar + 5, gsz);

    // phase 3: conv2 + heads + decode
    for (unsigned t = blockIdx.x; t < 1280; t += gsz) {
        int b = t / 20, y0 = (t - b * 20) * 4;
        head_tile(f2, wB2, c2_scale, c2_shift, reg_w, reg_b, obj_w, obj_b,
                  out, tile, b, y0, tid, lane, wv, l15, q);
    }
}

// ---------------------------------------------------------------------------
// Fallback standalone kernels (identical phase bodies).
// ---------------------------------------------------------------------------
__global__ __launch_bounds__(256) void rearr_w_kernel(
    const float* __restrict__ ws_, const float* __restrict__ w1,
    const float* __restrict__ w2,
    unsigned short* __restrict__ wS, unsigned short* __restrict__ wB1,
    unsigned short* __restrict__ wB2) {
    int idx = blockIdx.x * 256 + threadIdx.x;
    if (idx < 81920) rearr_elem(idx, ws_, w1, w2, wS, wB1, wB2);
}

__global__ __launch_bounds__(256) void stem_kernel(
    const float* __restrict__ x, const unsigned short* __restrict__ wS,
    const float* __restrict__ scale, const float* __restrict__ shift,
    unsigned short* __restrict__ f1) {
    int tid = threadIdx.x;
    int lane = tid & 63, wv = tid >> 6;
    stem_tile(x, wS, scale, shift, f1, blockIdx.y, blockIdx.x * 128,
              lane, wv, lane & 15, lane >> 4);
}

__global__ __launch_bounds__(256, 3) void conv3_kernel(
    const unsigned short* __restrict__ fin, const unsigned short* __restrict__ wB,
    const float* __restrict__ scale, const float* __restrict__ shift,
    unsigned short* __restrict__ fout) {
    __shared__ __align__(16) unsigned short tile[8 * CGS2];
    int tid = threadIdx.x;
    int lane = tid & 63, wv = tid >> 6;
    conv3_tile(fin, wB, scale, shift, fout, tile, blockIdx.y, blockIdx.x * 4,
               tid, lane, wv, lane & 15, lane >> 4);
}

__global__ __launch_bounds__(256, 3) void conv_head_kernel(
    const unsigned short* __restrict__ fin, const unsigned short* __restrict__ wB,
    const float* __restrict__ scale, const float* __restrict__ shift,
    const float* __restrict__ reg_w, const float* __restrict__ reg_b,
    const float* __restrict__ obj_w, const float* __restrict__ obj_b,
    float* __restrict__ out) {
    __shared__ __align__(16) unsigned short tile[8 * CGS2];
    int tid = threadIdx.x;
    int lane = tid & 63, wv = tid >> 6;
    head_tile(fin, wB, scale, shift, reg_w, reg_b, obj_w, obj_b, out, tile,
              blockIdx.y, blockIdx.x * 4, tid, lane, wv, lane & 15, lane >> 4);
}

// ---------------------------------------------------------------------------
extern "C" void kernel_launch(void* const* d_in, const int* in_sizes, int n_in,
                              void* d_out, int out_size, void* d_ws, size_t ws_size,
                              hipStream_t stream) {
    const float* x          = (const float*)d_in[0];
    const float* stem_w     = (const float*)d_in[1];
    const float* stem_scale = (const float*)d_in[2];
    const float* stem_shift = (const float*)d_in[3];
    const float* c1_w       = (const float*)d_in[4];
    const float* c1_scale   = (const float*)d_in[5];
    const float* c1_shift   = (const float*)d_in[6];
    const float* c2_w       = (const float*)d_in[7];
    const float* c2_scale   = (const float*)d_in[8];
    const float* c2_shift   = (const float*)d_in[9];
    const float* reg_w      = (const float*)d_in[10];
    const float* reg_b      = (const float*)d_in[11];
    const float* obj_w      = (const float*)d_in[12];
    const float* obj_b      = (const float*)d_in[13];
    float* out = (float*)d_out;

    // ws (ushort units): wS[8192] | wB1[36864] | wB2[36864] | f1 | f2 | bar
    const size_t needed =
        ((size_t)8192 + 73728 + 2 * (size_t)64 * NPIX * 64 + 32) * 2;
    if (ws_size < needed) return;

    unsigned short* ws  = (unsigned short*)d_ws;
    unsigned short* wS  = ws;
    unsigned short* wB1 = ws + 8192;
    unsigned short* wB2 = wB1 + 36864;
    unsigned short* f1  = wB2 + 36864;
    unsigned short* f2  = f1 + (size_t)64 * NPIX * 64;
    unsigned*       bar = (unsigned*)(f2 + (size_t)64 * NPIX * 64);

    // grid: prefer 640 (2.5/CU, divides 3200/1280) if occupancy allows,
    // else 512 (2/CU; conv phases then 2.5 tiles/block, mild imbalance).
    static int nblk = -1;
    if (nblk < 0) {
        int perCU = 0;
        if (hipOccupancyMaxActiveBlocksPerMultiprocessor(
                &perCU, (const void*)mega3_kernel, 256, 0) != hipSuccess)
            perCU = 0;
        int cap = perCU * 256;
        nblk = (cap >= 640) ? 640 : (cap >= 512 ? 512 : (cap >= 256 ? 256 : 0));
    }

    hipError_t e = hipErrorUnknown;
    if (nblk > 0) {
        hipMemsetAsync(bar, 0, 8 * sizeof(unsigned), stream);
        void* args[] = {
            (void*)&x,
            (void*)&stem_w, (void*)&stem_scale, (void*)&stem_shift,
            (void*)&c1_w, (void*)&c1_scale, (void*)&c1_shift,
            (void*)&c2_w, (void*)&c2_scale, (void*)&c2_shift,
            (void*)&reg_w, (void*)&reg_b, (void*)&obj_w, (void*)&obj_b,
            (void*)&out,
            (void*)&wS, (void*)&wB1, (void*)&wB2, (void*)&f1, (void*)&f2,
            (void*)&bar};
        e = hipLaunchCooperativeKernel(
            (const void*)mega3_kernel, dim3(nblk), dim3(256), args, 0, stream);
    }

    if (e != hipSuccess) {
        // fallback: proven 4-kernel path (R8)
        rearr_w_kernel<<<320, 256, 0, stream>>>(stem_w, c1_w, c2_w, wS, wB1, wB2);
        stem_kernel<<<dim3(50, 64), 256, 0, stream>>>(x, wS, stem_scale,
                                                      stem_shift, f1);
        conv3_kernel<<<dim3(20, 64), 256, 0, stream>>>(f1, wB1, c1_scale,
                                                       c1_shift, f2);
        conv_head_kernel<<<dim3(20, 64), 256, 0, stream>>>(
            f2, wB2, c2_scale, c2_shift, reg_w, reg_b, obj_w, obj_b, out);
    }
}

// Round 9
// 456.339 us; speedup vs baseline: 2.1858x; 1.8292x over previous
//
#include <hip/hip_runtime.h>
#include <cstdint>

// SREChead: stem 1x1 (128->64) + 2x 3x3 (64->64), each BN+SiLU, then 1x1
// reg(4)/obj(1) heads + YOLOX decode. B=64, 80x80, stride 32.
// R15: back to the proven multi-kernel structure (R8 = 441.7us), minus one
// launch: 4 dispatches -> 3. The persistent-kernel track is abandoned
// (best 834us; regular-launch grid barrier carries deadlock risk -- R14's
// ExceptionGroup is consistent with a hang; cooperative launches showed
// 36-267us variable residual).
//  - stem no longer needs the rearranged wS: its A-frag is 8 consecutive
//    floats of stem_w (co*128 + kb*32 + (lane>>4)*8) -> two aligned fx4
//    loads + 4 cvt_pk. stem_w is 32KB, L2-resident.
//  - conv-weight rearrange (wB1/wB2, 73728 elems) folded into the stem
//    launch as 288 extra blocks; consumed only by the NEXT kernels, so the
//    kernel boundary is the sync. No barrier, no co-residency assumption.
//  - conv3 / conv_head byte-identical to R8 (proven best).
// Prediction: one dispatch gap removed, 443 -> ~355-385us. If unchanged,
// the per-launch overhead model is wrong -> optimize stem next.

typedef short short8 __attribute__((ext_vector_type(8)));
typedef float floatx4 __attribute__((ext_vector_type(4)));
typedef float fx4 __attribute__((ext_vector_type(4)));
typedef unsigned short us4 __attribute__((ext_vector_type(4)));
typedef unsigned uint4v __attribute__((ext_vector_type(4)));
typedef unsigned uint2v __attribute__((ext_vector_type(2)));

#define NPIX 6400
#define CGS  3952    // conv tile granule stride: 494 px * 8 us (6x82=492 used)
#define CGS2 2576    // h-tile granule stride: 322 px * 8 us (320 used)
#define REARR_BLKS 288   // 73728 wB elements / 256

static __device__ __forceinline__ unsigned short f2bf(float f) {
    unsigned u = __builtin_bit_cast(unsigned, f);
    u += 0x7fffu + ((u >> 16) & 1u);      // round-to-nearest-even
    return (unsigned short)(u >> 16);
}

// packed bf16 convert: lo16 = bf16(a), hi16 = bf16(b); RTNE
static __device__ __forceinline__ unsigned cvt_pk_bf16(float a, float b) {
    unsigned r;
    asm("v_cvt_pk_bf16_f32 %0, %1, %2" : "=v"(r) : "v"(a), "v"(b));
    return r;
}

static __device__ __forceinline__ float silu_(float v) {
    return v / (1.0f + __expf(-v));
}

// ---------------------------------------------------------------------------
// Launch A: blocks [0,288) rearrange conv weights to MFMA A-frag order;
// blocks [288,3488) compute stem tiles (LDS-free, weights direct from
// stem_w). wB1/wB2 are consumed only by later kernels (boundary = sync).
//  wB layout: [kb(18)][ct(4)][lane][8] from w [64co][64ci][3][3]
//  co = ct*16+(lane&15); k = kb*32+(lane>>4)*8+j; ci=k&63, tap=k>>6.
// ---------------------------------------------------------------------------
__global__ __launch_bounds__(256) void stem_rearr_kernel(
    const float* __restrict__ x, const float* __restrict__ stem_w,
    const float* __restrict__ w1, const float* __restrict__ w2,
    const float* __restrict__ scale, const float* __restrict__ shift,
    unsigned short* __restrict__ f1,
    unsigned short* __restrict__ wB1, unsigned short* __restrict__ wB2) {
    int tid = threadIdx.x;

    if (blockIdx.x < REARR_BLKS) {
        int idx = blockIdx.x * 256 + tid;              // 0..73727
        const float* src = (idx < 36864) ? w1 : w2;
        unsigned short* dst = (idx < 36864) ? wB1 : wB2;
        int e = (idx < 36864) ? idx : idx - 36864;
        int j = e & 7, lane = (e >> 3) & 63, ct = (e >> 9) & 3, kb = e >> 11;
        int co = ct * 16 + (lane & 15);
        int k = kb * 32 + ((lane >> 4) * 8) + j;
        int ci = k & 63, tap = k >> 6;
        dst[e] = f2bf(src[(co * 64 + ci) * 9 + tap]);
        return;
    }

    // ---- stem tile ----
    int t = blockIdx.x - REARR_BLKS;                   // 0..3199
    int b = t / 50, pbase = (t - b * 50) * 128;
    int lane = tid & 63, wv = tid >> 6;
    int l15 = lane & 15, q = lane >> 4;

    floatx4 acc[4][2];   // [ct][t2]
    floatx4 zf = {0.0f, 0.0f, 0.0f, 0.0f};
    #pragma unroll
    for (int ct = 0; ct < 4; ++ct)
        #pragma unroll
        for (int t2 = 0; t2 < 2; ++t2) acc[ct][t2] = zf;

    const float* xb = x + (size_t)b * 128 * NPIX + pbase + wv * 32 + l15;

    #pragma unroll
    for (int kb = 0; kb < 4; ++kb) {
        // weight frags direct from stem_w: 8 consecutive floats at
        // co*128 + kb*32 + (lane>>4)*8  (32B-aligned -> two fx4)
        short8 wf[4];
        #pragma unroll
        for (int ct = 0; ct < 4; ++ct) {
            int co = ct * 16 + l15;
            const float* wsrc = stem_w + co * 128 + kb * 32 + q * 8;
            fx4 w0 = *(const fx4*)(wsrc);
            fx4 w1v = *(const fx4*)(wsrc + 4);
            uint4v u;
            u[0] = cvt_pk_bf16(w0[0], w0[1]);
            u[1] = cvt_pk_bf16(w0[2], w0[3]);
            u[2] = cvt_pk_bf16(w1v[0], w1v[1]);
            u[3] = cvt_pk_bf16(w1v[2], w1v[3]);
            wf[ct] = __builtin_bit_cast(short8, u);
        }
        short8 xf[2];
        #pragma unroll
        for (int t2 = 0; t2 < 2; ++t2) {
            const float* src = xb + (size_t)(kb * 32 + q * 8) * NPIX + t2 * 16;
            float v[8];
            #pragma unroll
            for (int j = 0; j < 8; ++j) v[j] = src[(size_t)j * NPIX];
            uint4v u;
            #pragma unroll
            for (int j = 0; j < 4; ++j) u[j] = cvt_pk_bf16(v[2 * j], v[2 * j + 1]);
            xf[t2] = __builtin_bit_cast(short8, u);
        }
        #pragma unroll
        for (int ct = 0; ct < 4; ++ct)
            #pragma unroll
            for (int t2 = 0; t2 < 2; ++t2)
                acc[ct][t2] = __builtin_amdgcn_mfma_f32_16x16x32_bf16(
                    wf[ct], xf[t2], acc[ct][t2], 0, 0, 0);
    }

    float sc[4][4], sh[4][4];
    #pragma unroll
    for (int ct = 0; ct < 4; ++ct)
        #pragma unroll
        for (int r = 0; r < 4; ++r) {
            sc[ct][r] = scale[ct * 16 + q * 4 + r];
            sh[ct][r] = shift[ct * 16 + q * 4 + r];
        }

    #pragma unroll
    for (int t2 = 0; t2 < 2; ++t2) {
        int pg = pbase + (wv * 2 + t2) * 16 + l15;
        unsigned short* dst = f1 + ((size_t)b * NPIX + pg) * 64;
        #pragma unroll
        for (int ct = 0; ct < 4; ++ct) {
            float r0 = silu_(acc[ct][t2][0] * sc[ct][0] + sh[ct][0]);
            float r1 = silu_(acc[ct][t2][1] * sc[ct][1] + sh[ct][1]);
            float r2 = silu_(acc[ct][t2][2] * sc[ct][2] + sh[ct][2]);
            float r3 = silu_(acc[ct][t2][3] * sc[ct][3] + sh[ct][3]);
            uint2v p2 = {cvt_pk_bf16(r0, r1), cvt_pk_bf16(r2, r3)};
            *(us4*)(dst + ct * 16 + q * 4) = __builtin_bit_cast(us4, p2);
        }
    }
}

// ---------------------------------------------------------------------------
// Conv core, 4-ct N-blocking (R6 structure, proven best).
static __device__ __forceinline__ void conv_core(
    const unsigned short* __restrict__ fin, const unsigned short* __restrict__ wB,
    unsigned short* tile, floatx4 (*acc)[5], int b, int y0,
    int tid, int lane, int wv, int l15, int q) {
    const unsigned short* fb = fin + (size_t)b * NPIX * 64;
    floatx4 zf = {0.0f, 0.0f, 0.0f, 0.0f};
    #pragma unroll
    for (int c4 = 0; c4 < 4; ++c4)
        #pragma unroll
        for (int pt = 0; pt < 5; ++pt) acc[c4][pt] = zf;

    #pragma unroll
    for (int half = 0; half < 2; ++half) {
        if (half) __syncthreads();     // WAR: half-0 reads done before restage
        #pragma unroll
        for (int i = 0; i < 8; ++i) {
            int cid = i * 256 + tid;   // 1968 = 492 pix * 4 granules
            if (cid < 1968) {
                int pixL = cid >> 2, g = cid & 3;
                int r = pixL / 82, c = pixL - r * 82;
                int gy = y0 - 1 + r, gx = c - 1;
                short8 v = {};
                if ((unsigned)gy < 80u && (unsigned)gx < 80u)
                    v = *(const short8*)(
                        fb + (size_t)(gy * 80 + gx) * 64 + half * 32 + g * 8);
                *(short8*)(tile + g * CGS + pixL * 8) = v;
            }
        }
        __syncthreads();

        #pragma unroll
        for (int trow = 0; trow < 3; ++trow) {
            const int dy = trow - 1;
            #pragma unroll
            for (int tc = 0; tc < 3; ++tc) {
                const int dx = tc - 1;
                const int kb = (trow * 3 + tc) * 2 + half;
                short8 w4[4];
                #pragma unroll
                for (int c4 = 0; c4 < 4; ++c4)
                    w4[c4] = *(const short8*)(wB + ((kb * 4 + c4) * 64 + lane) * 8);
                #pragma unroll
                for (int pt = 0; pt < 5; ++pt) {
                    int pix = (wv + 1 + dy) * 82 + pt * 16 + l15 + 1 + dx;
                    short8 b8 = *(const short8*)(tile + q * CGS + pix * 8);
                    #pragma unroll
                    for (int c4 = 0; c4 < 4; ++c4)
                        acc[c4][pt] = __builtin_amdgcn_mfma_f32_16x16x32_bf16(
                            w4[c4], b8, acc[c4][pt], 0, 0, 0);
                }
            }
        }
    }
}

// ---------------------------------------------------------------------------
__global__ __launch_bounds__(256, 3) void conv3_kernel(
    const unsigned short* __restrict__ fin, const unsigned short* __restrict__ wB,
    const float* __restrict__ scale, const float* __restrict__ shift,
    unsigned short* __restrict__ fout) {
    __shared__ __align__(16) unsigned short tile[8 * CGS2];  // 41216 B
    int b = blockIdx.y, y0 = blockIdx.x * 4;
    int tid = threadIdx.x;
    int lane = tid & 63, wv = tid >> 6;
    int l15 = lane & 15, q = lane >> 4;

    floatx4 acc[4][5];
    conv_core(fin, wB, tile, acc, b, y0, tid, lane, wv, l15, q);

    float sc4[4][4], sh4[4][4];
    #pragma unroll
    for (int c4 = 0; c4 < 4; ++c4)
        #pragma unroll
        for (int r = 0; r < 4; ++r) {
            sc4[c4][r] = scale[c4 * 16 + q * 4 + r];
            sh4[c4][r] = shift[c4 * 16 + q * 4 + r];
        }
    #pragma unroll
    for (int pt = 0; pt < 5; ++pt) {
        int pg = (y0 + wv) * 80 + pt * 16 + l15;
        unsigned short* dst = fout + ((size_t)b * NPIX + pg) * 64;
        #pragma unroll
        for (int c4 = 0; c4 < 4; ++c4) {
            float r0 = silu_(acc[c4][pt][0] * sc4[c4][0] + sh4[c4][0]);
            float r1 = silu_(acc[c4][pt][1] * sc4[c4][1] + sh4[c4][1]);
            float r2 = silu_(acc[c4][pt][2] * sc4[c4][2] + sh4[c4][2]);
            float r3 = silu_(acc[c4][pt][3] * sc4[c4][3] + sh4[c4][3]);
            uint2v p2 = {cvt_pk_bf16(r0, r1), cvt_pk_bf16(r2, r3)};
            *(us4*)(dst + c4 * 16 + q * 4) = __builtin_bit_cast(us4, p2);
        }
    }
}

// ---------------------------------------------------------------------------
__global__ __launch_bounds__(256, 3) void conv_head_kernel(
    const unsigned short* __restrict__ fin, const unsigned short* __restrict__ wB,
    const float* __restrict__ scale, const float* __restrict__ shift,
    const float* __restrict__ reg_w, const float* __restrict__ reg_b,
    const float* __restrict__ obj_w, const float* __restrict__ obj_b,
    float* __restrict__ out) {
    __shared__ __align__(16) unsigned short tile[8 * CGS2];  // 41216 B
    int b = blockIdx.y, y0 = blockIdx.x * 4;
    int tid = threadIdx.x;
    int lane = tid & 63, wv = tid >> 6;
    int l15 = lane & 15, q = lane >> 4;

    floatx4 acc[4][5];
    conv_core(fin, wB, tile, acc, b, y0, tid, lane, wv, l15, q);

    __syncthreads();   // conv reads done -> reuse LDS for h (stride CGS2)

    float sc4[4][4], sh4[4][4];
    #pragma unroll
    for (int c4 = 0; c4 < 4; ++c4)
        #pragma unroll
        for (int r = 0; r < 4; ++r) {
            sc4[c4][r] = scale[c4 * 16 + q * 4 + r];
            sh4[c4][r] = shift[c4 * 16 + q * 4 + r];
        }
    #pragma unroll
    for (int pt = 0; pt < 5; ++pt) {
        int pix = wv * 80 + pt * 16 + l15;   // block-local pixel 0..319
        #pragma unroll
        for (int c4 = 0; c4 < 4; ++c4) {
            int gco = c4 * 2 + (q >> 1);     // co>>3
            float r0 = silu_(acc[c4][pt][0] * sc4[c4][0] + sh4[c4][0]);
            float r1 = silu_(acc[c4][pt][1] * sc4[c4][1] + sh4[c4][1]);
            float r2 = silu_(acc[c4][pt][2] * sc4[c4][2] + sh4[c4][2]);
            float r3 = silu_(acc[c4][pt][3] * sc4[c4][3] + sh4[c4][3]);
            uint2v p2 = {cvt_pk_bf16(r0, r1), cvt_pk_bf16(r2, r3)};
            *(us4*)(tile + gco * CGS2 + pix * 8 + (q & 1) * 4) =
                __builtin_bit_cast(us4, p2);
        }
    }

    // head B-frags: B[k=co][n] = reg_w[n][co] (n<4), obj_w[co] (n==4), else 0
    short8 hbf[2];
    #pragma unroll
    for (int kb2 = 0; kb2 < 2; ++kb2) {
        int k0 = kb2 * 32 + q * 8;
        short8 f = {};
        if (l15 < 4) {
            #pragma unroll
            for (int j = 0; j < 8; ++j) f[j] = (short)f2bf(reg_w[l15 * 64 + k0 + j]);
        } else if (l15 == 4) {
            #pragma unroll
            for (int j = 0; j < 8; ++j) f[j] = (short)f2bf(obj_w[k0 + j]);
        }
        hbf[kb2] = f;
    }

    __syncthreads();

    floatx4 zf = {0.0f, 0.0f, 0.0f, 0.0f};
    floatx4 acc5[5];
    #pragma unroll
    for (int t = 0; t < 5; ++t) acc5[t] = zf;
    #pragma unroll
    for (int t = 0; t < 5; ++t) {
        int mt = wv * 5 + t;
        int pix = mt * 16 + l15;
        #pragma unroll
        for (int kb2 = 0; kb2 < 2; ++kb2) {
            short8 a = *(const short8*)(tile + (kb2 * 4 + q) * CGS2 + pix * 8);
            acc5[t] = __builtin_amdgcn_mfma_f32_16x16x32_bf16(
                a, hbf[kb2], acc5[t], 0, 0, 0);
        }
    }

    float bias = 0.0f;
    if (l15 < 4) bias = reg_b[l15];
    else if (l15 == 4) bias = obj_b[0];

    #pragma unroll
    for (int t = 0; t < 5; ++t) {
        int mt = wv * 5 + t;
        #pragma unroll
        for (int r = 0; r < 4; ++r) {
            int pixL = mt * 16 + q * 4 + r;
            if (l15 < 5) {
                float v = acc5[t][r] + bias;
                float gx = (float)(pixL % 80);
                float gy = (float)(y0 + pixL / 80);
                float o;
                if (l15 == 0)      o = (v + gx) * 32.0f;
                else if (l15 == 1) o = (v + gy) * 32.0f;
                else if (l15 < 4)  o = __expf(v) * 32.0f;
                else               o = 1.0f / (1.0f + __expf(-v));
                out[((size_t)b * NPIX + y0 * 80 + pixL) * 5 + l15] = o;
            }
        }
    }
}

// ---------------------------------------------------------------------------
extern "C" void kernel_launch(void* const* d_in, const int* in_sizes, int n_in,
                              void* d_out, int out_size, void* d_ws, size_t ws_size,
                              hipStream_t stream) {
    const float* x          = (const float*)d_in[0];
    const float* stem_w     = (const float*)d_in[1];
    const float* stem_scale = (const float*)d_in[2];
    const float* stem_shift = (const float*)d_in[3];
    const float* c1_w       = (const float*)d_in[4];
    const float* c1_scale   = (const float*)d_in[5];
    const float* c1_shift   = (const float*)d_in[6];
    const float* c2_w       = (const float*)d_in[7];
    const float* c2_scale   = (const float*)d_in[8];
    const float* c2_shift   = (const float*)d_in[9];
    const float* reg_w      = (const float*)d_in[10];
    const float* reg_b      = (const float*)d_in[11];
    const float* obj_w      = (const float*)d_in[12];
    const float* obj_b      = (const float*)d_in[13];
    float* out = (float*)d_out;

    // ws (ushort units): wB1[36864] | wB2[36864] | f1 | f2
    const size_t needed = ((size_t)73728 + 2 * (size_t)64 * NPIX * 64) * 2;
    if (ws_size < needed) return;

    unsigned short* ws  = (unsigned short*)d_ws;
    unsigned short* wB1 = ws;
    unsigned short* wB2 = wB1 + 36864;
    unsigned short* f1  = wB2 + 36864;
    unsigned short* f2  = f1 + (size_t)64 * NPIX * 64;

    // launch A: conv-weight rearrange (288 blocks) + stem (3200 blocks)
    stem_rearr_kernel<<<REARR_BLKS + 3200, 256, 0, stream>>>(
        x, stem_w, c1_w, c2_w, stem_scale, stem_shift, f1, wB1, wB2);
    conv3_kernel<<<dim3(20, 64), 256, 0, stream>>>(f1, wB1, c1_scale,
                                                   c1_shift, f2);
    conv_head_kernel<<<dim3(20, 64), 256, 0, stream>>>(
        f2, wB2, c2_scale, c2_shift, reg_w, reg_b, obj_w, obj_b, out);
}